// Round 5
// baseline (111.763 us; speedup 1.0000x reference)
//
#include <hip/hip_runtime.h>

constexpr int Nn = 64, Tt = 512, Vv = 17, Oo = 64;
constexpr int TV  = Tt * Vv;      // 8704
constexpr int CTV = 3 * TV;       // 26112
constexpr float EPSf = 1e-5f;
constexpr int GB1 = 512;          // K1 blocks
constexpr int RPB = 64;           // rows per K1 block
constexpr int NU  = 289;          // ordered (u,u') units
constexpr int GE  = 1792;         // padded gram entries (6*289+51 = 1785 used)
constexpr int BTV = 1088;         // 64*17 floats per c-plane chunk

// exact floor(v/17) for v < ~60000
__device__ inline int div17(int v) { return (int)(((unsigned)v * 61681u) >> 20); }

__device__ inline double wred(double v) {
#pragma unroll
  for (int o = 32; o > 0; o >>= 1) v += __shfl_down(v, o, 64);
  return v;
}

// ---------------------------------------------------------------------------
// K1: s-stat partials (5 f64/block) + x-Gram partials (1785 f32/block).
// Gram: M[cc'][u,u'] = sum_{n,t} xr[n,c,t,u]*xr[n,c',t,u'] (xr = raw (N,C,T,V) view)
__global__ void __launch_bounds__(256) k1(
    const float* __restrict__ x,
    const float* __restrict__ w1, const float* __restrict__ b1,
    const float* __restrict__ w2, const float* __restrict__ b2,
    const float* __restrict__ cw, const float* __restrict__ cb,
    double* __restrict__ spart, float* __restrict__ gpart)
{
  __shared__ float xsA[RPB * 51];   // 64 original (n,t) rows, contiguous chunk
  __shared__ float xsB[3 * BTV];    // 3 c-plane segments of the xr view
  __shared__ double dred[4][5];
  const int tid = threadIdx.x, bid = blockIdx.x;
  const int n = bid >> 3, ch = bid & 7;

  // stage xsA: flat [bid*3264, +3264)
  {
    const float4* src = (const float4*)(x + (size_t)bid * 3264);
    float4* dst = (float4*)xsA;
    for (int i = tid; i < 816; i += 256) dst[i] = src[i];
  }
  // stage xsB: 3 segments n*CTV + c*TV + ch*1088
#pragma unroll
  for (int c = 0; c < 3; ++c) {
    const float4* src = (const float4*)(x + (size_t)n * CTV + (size_t)c * TV + ch * BTV);
    float4* dst = (float4*)(xsB + c * BTV);
    for (int i = tid; i < 272; i += 256) dst[i] = src[i];
  }
  __syncthreads();

  // folded weights
  float u1[3], u2[3];
#pragma unroll
  for (int k = 0; k < 3; ++k) {
    float s1 = 0.f, s2 = 0.f;
#pragma unroll
    for (int c = 0; c < 3; ++c) { s1 += cw[c] * w1[c * 3 + k]; s2 += cw[c] * w2[c * 3 + k]; }
    u1[k] = s1; u2[k] = s2;
  }
  float d1 = 0.f, d2 = 0.f;
#pragma unroll
  for (int c = 0; c < 3; ++c) { d1 += b1[c] * cw[c]; d2 += b2[c] * cw[c]; }
  const float bb = cb[0];

  // s-stats: thread < 64 owns one original row
  double st[5] = {0, 0, 0, 0, 0};
  if (tid < RPB) {
    const float* rp = xsA + tid * 51;
    float A = 0.f, G = 0.f, Q1 = 0.f, Q2 = 0.f;
#pragma unroll
    for (int v = 0; v < 17; ++v) {
      float x0 = rp[v * 3], x1 = rp[v * 3 + 1], x2 = rp[v * 3 + 2];
      float va1 = fmaf(x0, u1[0], fmaf(x1, u1[1], fmaf(x2, u1[2], d1)));
      float va2 = fmaf(x0, u2[0], fmaf(x1, u2[1], fmaf(x2, u2[2], d2)));
      float g = bb - va2;
      A += va1; G += g;
      Q1 = fmaf(va1, va1, Q1); Q2 = fmaf(g, g, Q2);
    }
    st[0] = A; st[1] = G; st[2] = Q1; st[3] = Q2; st[4] = (double)A * (double)G;
  }
  {
    int wv = tid >> 6;
#pragma unroll
    for (int s = 0; s < 5; ++s) { double r = wred(st[s]); if ((tid & 63) == 0) dred[wv][s] = r; }
  }

  // Gram units (ordered (u,u')): 6 cc' pairs each
  float* gp = gpart + (size_t)bid * GE;
#pragma unroll
  for (int pass = 0; pass < 2; ++pass) {
    int k = tid + pass * 256;
    if (k < NU) {
      int u = div17(k), up = k - u * 17;
      float h0 = 0, h1 = 0, h2 = 0, h3 = 0, h4 = 0, h5 = 0;
      for (int t = 0; t < RPB; ++t) {
        int ro = t * 17;
        float a0 = xsB[ro + u],        a1 = xsB[BTV + ro + u],  a2 = xsB[2 * BTV + ro + u];
        float b0 = xsB[ro + up],       b1 = xsB[BTV + ro + up], b2 = xsB[2 * BTV + ro + up];
        h0 = fmaf(a0, b0, h0); h1 = fmaf(a0, b1, h1); h2 = fmaf(a0, b2, h2);
        h3 = fmaf(a1, b1, h3); h4 = fmaf(a1, b2, h4); h5 = fmaf(a2, b2, h5);
      }
      gp[0 * NU + k] = h0; gp[1 * NU + k] = h1; gp[2 * NU + k] = h2;
      gp[3 * NU + k] = h3; gp[4 * NU + k] = h4; gp[5 * NU + k] = h5;
    }
  }
  // means m[c][u]
  if (tid < 51) {
    int c = div17(tid), u = tid - c * 17;
    float m = 0.f;
    for (int t = 0; t < RPB; ++t) m += xsB[c * BTV + t * 17 + u];
    gp[6 * NU + tid] = m;
  }
  if (tid < GE - 1785) gp[1785 + tid] = 0.f;   // pad

  __syncthreads();
  if (tid < 5)
    spart[(size_t)bid * 5 + tid] = dred[0][tid] + dred[1][tid] + dred[2][tid] + dred[3][tid];
}

// ---------------------------------------------------------------------------
// K2: one block per n. s-stat global reduce (redundant), gram finalize (28/block),
// full-T a1/g staging, segmented a3 chain -> a3part[e][n] (transposed).
__global__ void __launch_bounds__(256) k2(
    const float* __restrict__ x, const double* __restrict__ spart,
    const float* __restrict__ gpart,
    const float* __restrict__ w1, const float* __restrict__ b1,
    const float* __restrict__ w2, const float* __restrict__ b2,
    const float* __restrict__ cw, const float* __restrict__ cb,
    const float* __restrict__ cg_, const float* __restrict__ cbeta,
    float* __restrict__ a3part, double* __restrict__ gramF)
{
  __shared__ float l1[Tt * Vv];     // 34816 B
  __shared__ float l2[Tt * Vv];     // 34816 B
  __shared__ float segsum[NU * 8];  // 9248 B
  __shared__ double dred[4][28];
  __shared__ float sfl[2];
  const int tid = threadIdx.x;
  const int n = blockIdx.x;
  const int wv = tid >> 6;

  // (a) reduce s-stat partials (512 rows)
  {
    double v5[5];
#pragma unroll
    for (int s = 0; s < 5; ++s)
      v5[s] = spart[(size_t)tid * 5 + s] + spart[(size_t)(tid + 256) * 5 + s];
#pragma unroll
    for (int s = 0; s < 5; ++s) { double r = wred(v5[s]); if ((tid & 63) == 0) dred[wv][s] = r; }
  }
  __syncthreads();
  if (tid == 0) {
    double S[5];
#pragma unroll
    for (int s = 0; s < 5; ++s) S[s] = dred[0][s] + dred[1][s] + dred[2][s] + dred[3][s];
    double cnt = (double)Nn * Tt * Vv * Vv;
    double mean = ((double)Vv * (S[0] + S[1])) / cnt;
    double m2   = ((double)Vv * (S[2] + S[3]) + 2.0 * S[4]) / cnt;
    double var  = m2 - mean * mean;
    double scale = (double)cg_[0] / sqrt(var + (double)EPSf);
    double shift = (double)cbeta[0] + scale * ((double)cb[0] - mean);
    sfl[0] = (float)scale; sfl[1] = (float)(shift - scale * (double)cb[0]);
  }
  __syncthreads();   // protects dred reuse below + publishes sfl

  // (b) gram finalize: entries [n*28, n*28+28)
  {
    int e0 = n * 28;
    const float* g1 = gpart + (size_t)tid * GE + e0;
    const float* g2 = gpart + (size_t)(tid + 256) * GE + e0;
    double gv[28];
#pragma unroll
    for (int k = 0; k < 28; ++k) gv[k] = (double)g1[k] + (double)g2[k];
#pragma unroll
    for (int k = 0; k < 28; ++k) { double r = wred(gv[k]); if ((tid & 63) == 0) dred[wv][k] = r; }
    __syncthreads();
    if (tid < 28)
      gramF[e0 + tid] = dred[0][tid] + dred[1][tid] + dred[2][tid] + dred[3][tid];
  }

  // (c) stage a1/g for the whole n (coalesced: flat idx over (t,v))
  float u1[3], u2[3];
#pragma unroll
  for (int k = 0; k < 3; ++k) {
    float s1 = 0.f, s2 = 0.f;
#pragma unroll
    for (int c = 0; c < 3; ++c) { s1 += cw[c] * w1[c * 3 + k]; s2 += cw[c] * w2[c * 3 + k]; }
    u1[k] = s1; u2[k] = s2;
  }
  float d1 = 0.f, d2 = 0.f;
#pragma unroll
  for (int c = 0; c < 3; ++c) { d1 += b1[c] * cw[c]; d2 += b2[c] * cw[c]; }
  const float bb = cb[0];

  const float* xb = x + (size_t)n * CTV;     // (N,T,V,C) chunk for this n
  for (int idx = tid; idx < Tt * Vv; idx += 256) {
    const float* xp = xb + idx * 3;
    float x0 = xp[0], x1 = xp[1], x2 = xp[2];
    float va1 = fmaf(x0, u1[0], fmaf(x1, u1[1], fmaf(x2, u1[2], d1)));
    float va2 = fmaf(x0, u2[0], fmaf(x1, u2[1], fmaf(x2, u2[2], d2)));
    l1[idx] = va1; l2[idx] = bb - va2;       // s_raw = l1[j] + l2[i]
  }
  __syncthreads();

  // (d) segmented a3 chain: 289 entries x 8 t-segments = 2312 balanced tasks
  {
    const float scale = sfl[0], c0 = sfl[1];
    for (int task = tid; task < NU * 8; task += 256) {
      int e = task >> 3, s = task & 7;
      int i = div17(e), j = e - i * 17;
      int r0 = s * 64;
      int dmax = (s == 7) ? (Tt - 1) : (r0 + 64);
      float prev = fmaxf(fmaf(scale, l1[r0 * 17 + j] + l2[r0 * 17 + i], c0), 0.f);
      float acc = 0.f;
      for (int d = r0 + 1; d <= dmax; ++d) {
        float cur = fmaxf(fmaf(scale, l1[d * 17 + j] + l2[d * 17 + i], c0), 0.f);
        acc += fabsf(cur - prev); prev = cur;
      }
      segsum[e * 8 + s] = acc;
    }
  }
  __syncthreads();

  // (e) deterministic segment sum -> transposed partials a3part[e][n]
  for (int e = tid; e < NU; e += 256) {
    float s = 0.f;
#pragma unroll
    for (int k = 0; k < 8; ++k) s += segsum[e * 8 + k];
    a3part[(size_t)e * Nn + n] = s;
  }
}

// ---------------------------------------------------------------------------
// K3: A (coalesced reduce) -> moments from Gram (parallel) -> coefs -> fused output
__global__ void __launch_bounds__(256, 2) k3(
    const float* __restrict__ x,
    const float* __restrict__ PA, const float* __restrict__ alpha,
    const float* __restrict__ a3part, const double* __restrict__ gramF,
    const float* __restrict__ c2w, const float* __restrict__ c2b,
    const float* __restrict__ bng, const float* __restrict__ bnb,
    const float* __restrict__ pw, const float* __restrict__ pb,
    const float* __restrict__ pg, const float* __restrict__ pbeta,
    float* __restrict__ out)
{
  __shared__ float xs[3 * BTV], ys[3 * BTV];
  __shared__ float As[NU], Bh[NU], rsA[17], coefs[512];
  __shared__ double gs[GE];
  __shared__ double mom[18];
  const int tid = threadIdx.x, bid = blockIdx.x;
  const int n = bid >> 3, ch = bid & 7;
  const int t0c = ch * BTV;

  // P0: stage xs (issue early; covered by the P1 barrier)
#pragma unroll
  for (int c = 0; c < 3; ++c) {
    const float4* src = (const float4*)(x + (size_t)n * CTV + (size_t)c * TV + t0c);
    float4* dst = (float4*)(xs + c * BTV);
    for (int i = tid; i < 272; i += 256) dst[i] = src[i];
  }

  // P1: load gram, reduce a3 (contiguous float4 per entry) -> A
  for (int e = tid; e < GE; e += 256) gs[e] = gramF[e];
  for (int e = tid; e < NU; e += 256) {
    const float4* ap = (const float4*)(a3part + (size_t)e * Nn);
    float4 a4 = ap[0];
#pragma unroll
    for (int q = 1; q < 16; ++q) {
      float4 b4 = ap[q];
      a4.x += b4.x; a4.y += b4.y; a4.z += b4.z; a4.w += b4.w;
    }
    float acc = (a4.x + a4.y) + (a4.z + a4.w);
    As[e] = fmaf(alpha[e], acc * (1.0f / Nn), PA[e]);
  }
  __syncthreads();

  // P2: B = A A^T (ordered units), row sums of A
  for (int k = tid; k < NU; k += 256) {
    int u = div17(k), up = k - u * 17;
    float s = 0.f;
#pragma unroll
    for (int v = 0; v < 17; ++v) s = fmaf(As[u * 17 + v], As[up * 17 + v], s);
    Bh[k] = s;
  }
  if (tid < 17) {
    float s = 0.f;
#pragma unroll
    for (int v = 0; v < 17; ++v) s += As[tid * 17 + v];
    rsA[tid] = s;
  }
  __syncthreads();

  // P3: 18 moments, parallel. 6 Eyy on 32-lane groups; small sums on lanes 192+.
  if (tid < 192) {
    int p = tid >> 5, r = tid & 31;
    double s = 0.0;
    for (int k = r; k < NU; k += 32) s += gs[p * NU + k] * (double)Bh[k];
#pragma unroll
    for (int off = 16; off > 0; off >>= 1) s += __shfl_down(s, off, 32);
    if (r == 0) mom[3 + p] = s;
  } else if (tid < 198) {              // Exx pairs (diagonal units)
    int p = tid - 192; double s = 0.0;
#pragma unroll
    for (int u = 0; u < 17; ++u) s += gs[p * NU + u * 18];
    mom[12 + p] = s;
  } else if (tid < 201) {              // sum y_c = sum_u m[c][u] * rowsumA[u]
    int c = tid - 198; double s = 0.0;
#pragma unroll
    for (int u = 0; u < 17; ++u) s += gs[6 * NU + c * 17 + u] * (double)rsA[u];
    mom[c] = s;
  } else if (tid < 204) {              // sum x_c
    int c = tid - 201; double s = 0.0;
#pragma unroll
    for (int u = 0; u < 17; ++u) s += gs[6 * NU + c * 17 + u];
    mom[9 + c] = s;
  }
  __syncthreads();

  // P4: per-o coefs, then y chunk into LDS
  if (tid < 64) {
    int o = tid;
    const double cnt = (double)Nn * Tt * Vv;
    double my0 = mom[0] / cnt, my1 = mom[1] / cnt, my2 = mom[2] / cnt;
    double e00 = mom[3] / cnt, e01 = mom[4] / cnt, e02 = mom[5] / cnt;
    double e11 = mom[6] / cnt, e12 = mom[7] / cnt, e22 = mom[8] / cnt;
    double mx0 = mom[9] / cnt, mx1 = mom[10] / cnt, mx2 = mom[11] / cnt;
    double f00 = mom[12] / cnt, f01 = mom[13] / cnt, f02 = mom[14] / cnt;
    double f11 = mom[15] / cnt, f12 = mom[16] / cnt, f22 = mom[17] / cnt;
    double w0 = c2w[o * 3], w1_ = c2w[o * 3 + 1], w2_ = c2w[o * 3 + 2], bz = c2b[o];
    double wm = w0 * my0 + w1_ * my1 + w2_ * my2, mz = wm + bz;
    double Ez2 = w0 * w0 * e00 + 2 * w0 * w1_ * e01 + 2 * w0 * w2_ * e02
               + w1_ * w1_ * e11 + 2 * w1_ * w2_ * e12 + w2_ * w2_ * e22
               + 2 * bz * wm + bz * bz;
    double sz = (double)bng[o] / sqrt(Ez2 - mz * mz + (double)EPSf);
    double q0 = pw[o * 3], q1 = pw[o * 3 + 1], q2 = pw[o * 3 + 2], bp = pb[o];
    double qm = q0 * mx0 + q1 * mx1 + q2 * mx2, mp = qm + bp;
    double Ep2 = q0 * q0 * f00 + 2 * q0 * q1 * f01 + 2 * q0 * q2 * f02
               + q1 * q1 * f11 + 2 * q1 * q2 * f12 + q2 * q2 * f22
               + 2 * bp * qm + bp * bp;
    double sp = (double)pg[o] / sqrt(Ep2 - mp * mp + (double)EPSf);
    coefs[o * 8 + 0] = (float)(sz * w0); coefs[o * 8 + 1] = (float)(sz * w1_); coefs[o * 8 + 2] = (float)(sz * w2_);
    coefs[o * 8 + 3] = (float)(sp * q0); coefs[o * 8 + 4] = (float)(sp * q1); coefs[o * 8 + 5] = (float)(sp * q2);
    coefs[o * 8 + 6] = (float)(sz * (bz - mz) + (double)bnb[o] + sp * (bp - mp) + (double)pbeta[o]);
    coefs[o * 8 + 7] = 0.f;
  }
#pragma unroll
  for (int k = 0; k < 5; ++k) {
    int e = k * 256 + tid;
    if (e < BTV) {
      int tr = div17(e), v = e - tr * 17;
      float y0 = 0.f, y1 = 0.f, y2 = 0.f;
#pragma unroll
      for (int u = 0; u < 17; ++u) {
        float a = As[u * 17 + v];
        y0 = fmaf(xs[tr * 17 + u], a, y0);
        y1 = fmaf(xs[BTV + tr * 17 + u], a, y1);
        y2 = fmaf(xs[2 * BTV + tr * 17 + u], a, y2);
      }
      ys[e] = y0; ys[BTV + e] = y1; ys[2 * BTV + e] = y2;
    }
  }
  __syncthreads();

  // P5: fused output
  float* ob = out + (size_t)n * ((size_t)Oo * TV) + t0c;
#pragma unroll 2
  for (int k = 0; k < 68; ++k) {          // 68*256 = 64 o * 272 float4
    int idx = k * 256 + tid;
    int o = div17(idx >> 4);
    int q = idx - o * 272, tq = q * 4;
    float4 y0 = *(const float4*)&ys[tq];
    float4 y1 = *(const float4*)&ys[BTV + tq];
    float4 y2 = *(const float4*)&ys[2 * BTV + tq];
    float4 x0 = *(const float4*)&xs[tq];
    float4 x1 = *(const float4*)&xs[BTV + tq];
    float4 x2 = *(const float4*)&xs[2 * BTV + tq];
    float a0 = coefs[o * 8 + 0], a1 = coefs[o * 8 + 1], a2 = coefs[o * 8 + 2];
    float p0 = coefs[o * 8 + 3], p1 = coefs[o * 8 + 4], p2 = coefs[o * 8 + 5];
    float be = coefs[o * 8 + 6];
    float4 r;
    r.x = fmaxf(fmaf(a0, y0.x, fmaf(a1, y1.x, fmaf(a2, y2.x, fmaf(p0, x0.x, fmaf(p1, x1.x, fmaf(p2, x2.x, be)))))), 0.f);
    r.y = fmaxf(fmaf(a0, y0.y, fmaf(a1, y1.y, fmaf(a2, y2.y, fmaf(p0, x0.y, fmaf(p1, x1.y, fmaf(p2, x2.y, be)))))), 0.f);
    r.z = fmaxf(fmaf(a0, y0.z, fmaf(a1, y1.z, fmaf(a2, y2.z, fmaf(p0, x0.z, fmaf(p1, x1.z, fmaf(p2, x2.z, be)))))), 0.f);
    r.w = fmaxf(fmaf(a0, y0.w, fmaf(a1, y1.w, fmaf(a2, y2.w, fmaf(p0, x0.w, fmaf(p1, x1.w, fmaf(p2, x2.w, be)))))), 0.f);
    *(float4*)(ob + (size_t)o * TV + tq) = r;
  }
}

extern "C" void kernel_launch(void* const* d_in, const int* in_sizes, int n_in,
                              void* d_out, int out_size, void* d_ws, size_t ws_size,
                              hipStream_t stream)
{
  (void)in_sizes; (void)n_in; (void)out_size; (void)ws_size;
  const float* x     = (const float*)d_in[0];
  const float* w1    = (const float*)d_in[1];
  const float* b1    = (const float*)d_in[2];
  const float* w2    = (const float*)d_in[3];
  const float* b2    = (const float*)d_in[4];
  const float* cw    = (const float*)d_in[5];
  const float* cb    = (const float*)d_in[6];
  const float* cg_   = (const float*)d_in[7];
  const float* cbeta = (const float*)d_in[8];
  const float* PA    = (const float*)d_in[9];
  const float* alpha = (const float*)d_in[10];
  const float* c2w   = (const float*)d_in[11];
  const float* c2b   = (const float*)d_in[12];
  const float* bng   = (const float*)d_in[13];
  const float* bnb   = (const float*)d_in[14];
  const float* pw    = (const float*)d_in[15];
  const float* pb    = (const float*)d_in[16];
  const float* pg    = (const float*)d_in[17];
  const float* pbeta = (const float*)d_in[18];
  float* out = (float*)d_out;

  char* ws = (char*)d_ws;
  double* spart  = (double*)(ws + 0);          // 512*5*8    = 20480
  float*  gpart  = (float*)(ws + 20480);       // 512*1792*4 = 3670016 -> 3690496
  float*  a3part = (float*)(ws + 3690496);     // 289*64*4   = 73984   -> 3764480
  double* gramF  = (double*)(ws + 3764480);    // 1792*8     = 14336   -> 3778816

  hipLaunchKernelGGL(k1, dim3(GB1), dim3(256), 0, stream,
                     x, w1, b1, w2, b2, cw, cb, spart, gpart);
  hipLaunchKernelGGL(k2, dim3(Nn), dim3(256), 0, stream,
                     x, spart, gpart, w1, b1, w2, b2, cw, cb, cg_, cbeta, a3part, gramF);
  hipLaunchKernelGGL(k3, dim3(512), dim3(256), 0, stream,
                     x, PA, alpha, a3part, gramF, c2w, c2b, bng, bnb,
                     pw, pb, pg, pbeta, out);
}

// Round 6
// 89.225 us; speedup vs baseline: 1.2526x; 1.2526x over previous
//
#include <hip/hip_runtime.h>

constexpr int Nn = 64, Tt = 512, Vv = 17, Oo = 64;
constexpr int TV  = Tt * Vv;      // 8704
constexpr int CTV = 3 * TV;       // 26112
constexpr float EPSf = 1e-5f;
constexpr int NG   = 51;          // gram dimension (c*17+u)
constexpr int GSTR = 2688;        // gpart per-block stride (floats); 51*51+51 = 2652 used
constexpr int NGE  = 2652;
constexpr int BTV  = 1088;        // 64*17

// exact floor(v/17) for v < ~60000
__device__ inline int div17(int v) { return (int)(((unsigned)v * 61681u) >> 20); }

__device__ inline double wred(double v) {
#pragma unroll
  for (int o = 32; o > 0; o >>= 1) v += __shfl_down(v, o, 64);
  return v;
}

// ---------------------------------------------------------------------------
// K1: 512 blocks. s-stat partials (5 f64) + 51x51 xr-gram partials + col means.
__global__ void __launch_bounds__(256) k1(
    const float* __restrict__ x,
    const float* __restrict__ w1, const float* __restrict__ b1,
    const float* __restrict__ w2, const float* __restrict__ b2,
    const float* __restrict__ cw, const float* __restrict__ cb,
    double* __restrict__ spart, float* __restrict__ gpart)
{
  __shared__ float wr[64 * 56];    // xr-view rows, padded 51->56, zeros in pad
  __shared__ float xsA[64 * 51];   // original (n,t,v,c) rows (contiguous chunk)
  __shared__ double dred[4][5];
  const int tid = threadIdx.x, bid = blockIdx.x;
  const int n = bid >> 3, ch = bid & 7;

  // stage xsA: contiguous flat chunk [bid*3264, +3264)
  {
    const float4* src = (const float4*)(x + (size_t)bid * 3264);
    float4* dst = (float4*)xsA;
    for (int i = tid; i < 816; i += 256) dst[i] = src[i];
  }
  // stage wr: three c-plane segments, scatter into padded rows
#pragma unroll
  for (int c = 0; c < 3; ++c) {
    const float4* src = (const float4*)(x + (size_t)n * CTV + (size_t)c * TV + ch * BTV);
    for (int i = tid; i < 272; i += 256) {
      float4 v = src[i];
      int p = i * 4;
      float vv[4] = { v.x, v.y, v.z, v.w };
#pragma unroll
      for (int k = 0; k < 4; ++k) {
        int pp = p + k; int t = div17(pp), u = pp - t * 17;
        wr[t * 56 + c * 17 + u] = vv[k];
      }
    }
  }
  // zero pad cols 51..55
  for (int i = tid; i < 64 * 5; i += 256) { int t = i / 5, j = 51 + (i - t * 5); wr[t * 56 + j] = 0.f; }
  __syncthreads();

  // folded weights
  float u1[3], u2[3];
#pragma unroll
  for (int k = 0; k < 3; ++k) {
    float s1 = 0.f, s2 = 0.f;
#pragma unroll
    for (int c = 0; c < 3; ++c) { s1 += cw[c] * w1[c * 3 + k]; s2 += cw[c] * w2[c * 3 + k]; }
    u1[k] = s1; u2[k] = s2;
  }
  float d1 = 0.f, d2 = 0.f;
#pragma unroll
  for (int c = 0; c < 3; ++c) { d1 += b1[c] * cw[c]; d2 += b2[c] * cw[c]; }
  const float bb = cb[0];

  // --- gram: threads 0..48, 8x8 register tile, b128 edge reads (broadcast) ---
  if (tid < 49) {
    const int r8 = (tid / 7) * 8, c8 = (tid - (tid / 7) * 7) * 8;
    float acc[8][8];
#pragma unroll
    for (int a = 0; a < 8; ++a)
#pragma unroll
      for (int b = 0; b < 8; ++b) acc[a][b] = 0.f;
    for (int t = 0; t < 64; ++t) {
      const float* row = &wr[t * 56];
      float4 ra0 = *(const float4*)(row + r8), ra1 = *(const float4*)(row + r8 + 4);
      float4 cb0 = *(const float4*)(row + c8), cb1 = *(const float4*)(row + c8 + 4);
      float ae[8] = { ra0.x, ra0.y, ra0.z, ra0.w, ra1.x, ra1.y, ra1.z, ra1.w };
      float be[8] = { cb0.x, cb0.y, cb0.z, cb0.w, cb1.x, cb1.y, cb1.z, cb1.w };
#pragma unroll
      for (int a = 0; a < 8; ++a)
#pragma unroll
        for (int b = 0; b < 8; ++b) acc[a][b] = fmaf(ae[a], be[b], acc[a][b]);
    }
    float* gp = gpart + (size_t)bid * GSTR;
#pragma unroll
    for (int a = 0; a < 8; ++a) {
      int j = r8 + a;
      if (j < NG) {
#pragma unroll
        for (int b = 0; b < 8; ++b) {
          int jp = c8 + b;
          if (jp < NG) gp[j * NG + jp] = acc[a][b];
        }
      }
    }
  }

  // --- s-stats: threads 64..127 (one original row each) ---
  double st[5] = {0, 0, 0, 0, 0};
  if (tid >= 64 && tid < 128) {
    const float* rp = &xsA[(tid - 64) * 51];
    float A = 0.f, G = 0.f, Q1 = 0.f, Q2 = 0.f;
#pragma unroll
    for (int v = 0; v < 17; ++v) {
      float x0 = rp[v * 3], x1 = rp[v * 3 + 1], x2 = rp[v * 3 + 2];
      float va1 = fmaf(x0, u1[0], fmaf(x1, u1[1], fmaf(x2, u1[2], d1)));
      float va2 = fmaf(x0, u2[0], fmaf(x1, u2[1], fmaf(x2, u2[2], d2)));
      float g = bb - va2;
      A += va1; G += g;
      Q1 = fmaf(va1, va1, Q1); Q2 = fmaf(g, g, Q2);
    }
    st[0] = A; st[1] = G; st[2] = Q1; st[3] = Q2; st[4] = (double)A * (double)G;
  }
  // --- means: threads 128..178 ---
  if (tid >= 128 && tid < 128 + NG) {
    int j = tid - 128;
    float m = 0.f;
    for (int t = 0; t < 64; ++t) m += wr[t * 56 + j];
    gpart[(size_t)bid * GSTR + NG * NG + j] = m;
  }

  {
    int wv = tid >> 6;
#pragma unroll
    for (int s = 0; s < 5; ++s) { double r = wred(st[s]); if ((tid & 63) == 0) dred[wv][s] = r; }
  }
  __syncthreads();
  if (tid < 5)
    spart[(size_t)bid * 5 + tid] = dred[0][tid] + dred[1][tid] + dred[2][tid] + dred[3][tid];
}

// ---------------------------------------------------------------------------
// K2: 128 blocks (h, n). s-stat global reduce, gram finalize (21 entries/block),
// transposed a1/g staging, b128 segmented a3 chain -> a3part[block][e].
__global__ void __launch_bounds__(256) k2(
    const float* __restrict__ x, const double* __restrict__ spart,
    const float* __restrict__ gpart,
    const float* __restrict__ w1, const float* __restrict__ b1,
    const float* __restrict__ w2, const float* __restrict__ b2,
    const float* __restrict__ cw, const float* __restrict__ cb,
    const float* __restrict__ cg_, const float* __restrict__ cbeta,
    float* __restrict__ a3part, double* __restrict__ gramF)
{
  __shared__ float l1t[17 * 260];   // [v][t] transposed, cols t0..t0+256
  __shared__ float l2t[17 * 260];
  __shared__ float segsum[289 * 4];
  __shared__ double dred[4][21];
  __shared__ float sfl[2];
  const int tid = threadIdx.x;
  const int h = blockIdx.x, n = blockIdx.y;
  const int jb = n * 2 + h;
  const int t0 = h * 256;
  const int wv = tid >> 6;

  // (a) global s-stat reduce (redundant per block)
  {
    double v5[5];
#pragma unroll
    for (int s = 0; s < 5; ++s)
      v5[s] = spart[(size_t)tid * 5 + s] + spart[(size_t)(tid + 256) * 5 + s];
#pragma unroll
    for (int s = 0; s < 5; ++s) { double r = wred(v5[s]); if ((tid & 63) == 0) dred[wv][s] = r; }
  }
  __syncthreads();
  if (tid == 0) {
    double S[5];
#pragma unroll
    for (int s = 0; s < 5; ++s) S[s] = dred[0][s] + dred[1][s] + dred[2][s] + dred[3][s];
    double cnt = (double)Nn * Tt * Vv * Vv;
    double mean = ((double)Vv * (S[0] + S[1])) / cnt;
    double m2   = ((double)Vv * (S[2] + S[3]) + 2.0 * S[4]) / cnt;
    double var  = m2 - mean * mean;
    double scale = (double)cg_[0] / sqrt(var + (double)EPSf);
    double shift = (double)cbeta[0] + scale * ((double)cb[0] - mean);
    sfl[0] = (float)scale; sfl[1] = (float)(shift - scale * (double)cb[0]);
  }
  __syncthreads();

  // (b) gram finalize: entries [jb*21, jb*21+21), reduce over 512 block-partials
  {
    int e0 = jb * 21;
    double gv[21];
    const float* g1 = gpart + (size_t)tid * GSTR + e0;
    const float* g2 = gpart + (size_t)(tid + 256) * GSTR + e0;
#pragma unroll
    for (int k = 0; k < 21; ++k) gv[k] = (double)g1[k] + (double)g2[k];
#pragma unroll
    for (int k = 0; k < 21; ++k) { double r = wred(gv[k]); if ((tid & 63) == 0) dred[wv][k] = r; }
    __syncthreads();
    if (tid < 21 && e0 + tid < NGE)
      gramF[e0 + tid] = dred[0][tid] + dred[1][tid] + dred[2][tid] + dred[3][tid];
  }

  // (c) stage a1/g transposed
  float u1[3], u2[3];
#pragma unroll
  for (int k = 0; k < 3; ++k) {
    float s1 = 0.f, s2 = 0.f;
#pragma unroll
    for (int c = 0; c < 3; ++c) { s1 += cw[c] * w1[c * 3 + k]; s2 += cw[c] * w2[c * 3 + k]; }
    u1[k] = s1; u2[k] = s2;
  }
  float d1 = 0.f, d2 = 0.f;
#pragma unroll
  for (int c = 0; c < 3; ++c) { d1 += b1[c] * cw[c]; d2 += b2[c] * cw[c]; }
  const float bb = cb[0];

  const int nst = (h == 0) ? 257 : 256;   // staged cols (incl. boundary row)
  const float* xb = x + ((size_t)(n * Tt + t0)) * 51;
  for (int idx = tid; idx < nst * 17; idx += 256) {
    int r = div17(idx), v = idx - r * 17;
    const float* xp = xb + idx * 3;
    float x0 = xp[0], x1 = xp[1], x2 = xp[2];
    float va1 = fmaf(x0, u1[0], fmaf(x1, u1[1], fmaf(x2, u1[2], d1)));
    float va2 = fmaf(x0, u2[0], fmaf(x1, u2[1], fmaf(x2, u2[2], d2)));
    l1t[v * 260 + r] = va1; l2t[v * 260 + r] = bb - va2;
  }
  __syncthreads();

  // (d) chain: 289 entries x 4 segments of 64, b128 reads
  {
    const float scale = sfl[0], c0 = sfl[1];
    for (int task = tid; task < 289 * 4; task += 256) {
      int e = task >> 2, s = task & 3;
      int i = div17(e), j = e - i * 17;
      int ts = s * 64;
      bool hasb = !(h == 1 && s == 3);    // boundary element ts+64 exists
      const float* J = &l1t[j * 260];
      const float* I = &l2t[i * 260];
      float prev = fmaxf(fmaf(scale, J[ts] + I[ts], c0), 0.f);
      float acc = 0.f;
#pragma unroll 4
      for (int q = 0; q < 16; ++q) {
        float4 a4 = *(const float4*)(J + ts + q * 4);
        float4 b4 = *(const float4*)(I + ts + q * 4);
        float z0 = fmaxf(fmaf(scale, a4.x + b4.x, c0), 0.f);
        float z1 = fmaxf(fmaf(scale, a4.y + b4.y, c0), 0.f);
        float z2 = fmaxf(fmaf(scale, a4.z + b4.z, c0), 0.f);
        float z3 = fmaxf(fmaf(scale, a4.w + b4.w, c0), 0.f);
        if (q > 0) acc += fabsf(z0 - prev);
        acc += fabsf(z1 - z0) + fabsf(z2 - z1) + fabsf(z3 - z2);
        prev = z3;
      }
      if (hasb) {
        float zb = fmaxf(fmaf(scale, J[ts + 64] + I[ts + 64], c0), 0.f);
        acc += fabsf(zb - prev);
      }
      segsum[e * 4 + s] = acc;
    }
  }
  __syncthreads();

  // (e) segment sum -> a3part[jb][e]
  for (int e = tid; e < 289; e += 256) {
    float s = (segsum[e * 4] + segsum[e * 4 + 1]) + (segsum[e * 4 + 2] + segsum[e * 4 + 3]);
    a3part[(size_t)jb * 289 + e] = s;
  }
}

// ---------------------------------------------------------------------------
// K3: A (coalesced reduce) -> moments from gram -> coefs -> fused output
__global__ void __launch_bounds__(256, 2) k3(
    const float* __restrict__ x,
    const float* __restrict__ PA, const float* __restrict__ alpha,
    const float* __restrict__ a3part, const double* __restrict__ gramF,
    const float* __restrict__ c2w, const float* __restrict__ c2b,
    const float* __restrict__ bng, const float* __restrict__ bnb,
    const float* __restrict__ pw, const float* __restrict__ pb,
    const float* __restrict__ pg, const float* __restrict__ pbeta,
    float* __restrict__ out)
{
  __shared__ float xs[3 * BTV], ys[3 * BTV];
  __shared__ float As[289], Bh[289], rsA[17], coefs[512];
  __shared__ double gs[NGE];
  __shared__ double mom[18];
  const int tid = threadIdx.x, bid = blockIdx.x;
  const int n = bid >> 3, ch = bid & 7;
  const int t0c = ch * BTV;

  // P0: stage xs early
#pragma unroll
  for (int c = 0; c < 3; ++c) {
    const float4* src = (const float4*)(x + (size_t)n * CTV + (size_t)c * TV + t0c);
    float4* dst = (float4*)(xs + c * BTV);
    for (int i = tid; i < 272; i += 256) dst[i] = src[i];
  }

  // P1: load gram + reduce a3 (lanes over e: coalesced) -> A
  for (int e = tid; e < NGE; e += 256) gs[e] = gramF[e];
  for (int e = tid; e < 289; e += 256) {
    float acc = 0.f;
#pragma unroll 4
    for (int j = 0; j < 128; ++j) acc += a3part[(size_t)j * 289 + e];
    As[e] = fmaf(alpha[e], acc * (1.0f / Nn), PA[e]);
  }
  __syncthreads();

  // P2: B = A A^T (ordered units), row sums of A
  for (int k = tid; k < 289; k += 256) {
    int u = div17(k), up = k - u * 17;
    float s = 0.f;
#pragma unroll
    for (int v = 0; v < 17; ++v) s = fmaf(As[u * 17 + v], As[up * 17 + v], s);
    Bh[k] = s;
  }
  if (tid < 17) {
    float s = 0.f;
#pragma unroll
    for (int v = 0; v < 17; ++v) s += As[tid * 17 + v];
    rsA[tid] = s;
  }
  __syncthreads();

  // P3: 18 moments (gram is [j][j'] with j = c*17+u; means at NG*NG+)
  {
    const int pc0[6] = {0, 0, 0, 1, 1, 2};
    const int pc1[6] = {0, 1, 2, 1, 2, 2};
    if (tid < 192) {
      int p = tid >> 5, r = tid & 31;
      int c = pc0[p], cp = pc1[p];
      double s = 0.0;
      for (int k = r; k < 289; k += 32) {
        int u = div17(k), up = k - u * 17;
        s += gs[(c * 17 + u) * NG + cp * 17 + up] * (double)Bh[k];
      }
#pragma unroll
      for (int off = 16; off > 0; off >>= 1) s += __shfl_down(s, off, 32);
      if (r == 0) mom[3 + p] = s;
    } else if (tid < 198) {              // Exx pairs: diagonal u=up
      int p = tid - 192; int c = pc0[p], cp = pc1[p];
      double s = 0.0;
#pragma unroll
      for (int u = 0; u < 17; ++u) s += gs[(c * 17 + u) * NG + cp * 17 + u];
      mom[12 + p] = s;
    } else if (tid < 201) {              // sum y_c
      int c = tid - 198; double s = 0.0;
#pragma unroll
      for (int u = 0; u < 17; ++u) s += gs[NG * NG + c * 17 + u] * (double)rsA[u];
      mom[c] = s;
    } else if (tid < 204) {              // sum x_c
      int c = tid - 201; double s = 0.0;
#pragma unroll
      for (int u = 0; u < 17; ++u) s += gs[NG * NG + c * 17 + u];
      mom[9 + c] = s;
    }
  }
  __syncthreads();

  // P4: per-o coefs + y chunk into LDS
  if (tid < 64) {
    int o = tid;
    const double cnt = (double)Nn * Tt * Vv;
    double my0 = mom[0] / cnt, my1 = mom[1] / cnt, my2 = mom[2] / cnt;
    double e00 = mom[3] / cnt, e01 = mom[4] / cnt, e02 = mom[5] / cnt;
    double e11 = mom[6] / cnt, e12 = mom[7] / cnt, e22 = mom[8] / cnt;
    double mx0 = mom[9] / cnt, mx1 = mom[10] / cnt, mx2 = mom[11] / cnt;
    double f00 = mom[12] / cnt, f01 = mom[13] / cnt, f02 = mom[14] / cnt;
    double f11 = mom[15] / cnt, f12 = mom[16] / cnt, f22 = mom[17] / cnt;
    double w0 = c2w[o * 3], w1_ = c2w[o * 3 + 1], w2_ = c2w[o * 3 + 2], bz = c2b[o];
    double wm = w0 * my0 + w1_ * my1 + w2_ * my2, mz = wm + bz;
    double Ez2 = w0 * w0 * e00 + 2 * w0 * w1_ * e01 + 2 * w0 * w2_ * e02
               + w1_ * w1_ * e11 + 2 * w1_ * w2_ * e12 + w2_ * w2_ * e22
               + 2 * bz * wm + bz * bz;
    double sz = (double)bng[o] / sqrt(Ez2 - mz * mz + (double)EPSf);
    double q0 = pw[o * 3], q1 = pw[o * 3 + 1], q2 = pw[o * 3 + 2], bp = pb[o];
    double qm = q0 * mx0 + q1 * mx1 + q2 * mx2, mp = qm + bp;
    double Ep2 = q0 * q0 * f00 + 2 * q0 * q1 * f01 + 2 * q0 * q2 * f02
               + q1 * q1 * f11 + 2 * q1 * q2 * f12 + q2 * q2 * f22
               + 2 * bp * qm + bp * bp;
    double sp = (double)pg[o] / sqrt(Ep2 - mp * mp + (double)EPSf);
    coefs[o * 8 + 0] = (float)(sz * w0); coefs[o * 8 + 1] = (float)(sz * w1_); coefs[o * 8 + 2] = (float)(sz * w2_);
    coefs[o * 8 + 3] = (float)(sp * q0); coefs[o * 8 + 4] = (float)(sp * q1); coefs[o * 8 + 5] = (float)(sp * q2);
    coefs[o * 8 + 6] = (float)(sz * (bz - mz) + (double)bnb[o] + sp * (bp - mp) + (double)pbeta[o]);
    coefs[o * 8 + 7] = 0.f;
  }
#pragma unroll
  for (int k = 0; k < 5; ++k) {
    int e = k * 256 + tid;
    if (e < BTV) {
      int tr = div17(e), v = e - tr * 17;
      float y0 = 0.f, y1 = 0.f, y2 = 0.f;
#pragma unroll
      for (int u = 0; u < 17; ++u) {
        float a = As[u * 17 + v];
        y0 = fmaf(xs[tr * 17 + u], a, y0);
        y1 = fmaf(xs[BTV + tr * 17 + u], a, y1);
        y2 = fmaf(xs[2 * BTV + tr * 17 + u], a, y2);
      }
      ys[e] = y0; ys[BTV + e] = y1; ys[2 * BTV + e] = y2;
    }
  }
  __syncthreads();

  // P5: fused output
  float* ob = out + (size_t)n * ((size_t)Oo * TV) + t0c;
#pragma unroll 2
  for (int k = 0; k < 68; ++k) {          // 68*256 = 64 o * 272 float4
    int idx = k * 256 + tid;
    int o = div17(idx >> 4);
    int q = idx - o * 272, tq = q * 4;
    float4 y0 = *(const float4*)&ys[tq];
    float4 y1 = *(const float4*)&ys[BTV + tq];
    float4 y2 = *(const float4*)&ys[2 * BTV + tq];
    float4 x0 = *(const float4*)&xs[tq];
    float4 x1 = *(const float4*)&xs[BTV + tq];
    float4 x2 = *(const float4*)&xs[2 * BTV + tq];
    float a0 = coefs[o * 8 + 0], a1 = coefs[o * 8 + 1], a2 = coefs[o * 8 + 2];
    float p0 = coefs[o * 8 + 3], p1 = coefs[o * 8 + 4], p2 = coefs[o * 8 + 5];
    float be = coefs[o * 8 + 6];
    float4 r;
    r.x = fmaxf(fmaf(a0, y0.x, fmaf(a1, y1.x, fmaf(a2, y2.x, fmaf(p0, x0.x, fmaf(p1, x1.x, fmaf(p2, x2.x, be)))))), 0.f);
    r.y = fmaxf(fmaf(a0, y0.y, fmaf(a1, y1.y, fmaf(a2, y2.y, fmaf(p0, x0.y, fmaf(p1, x1.y, fmaf(p2, x2.y, be)))))), 0.f);
    r.z = fmaxf(fmaf(a0, y0.z, fmaf(a1, y1.z, fmaf(a2, y2.z, fmaf(p0, x0.z, fmaf(p1, x1.z, fmaf(p2, x2.z, be)))))), 0.f);
    r.w = fmaxf(fmaf(a0, y0.w, fmaf(a1, y1.w, fmaf(a2, y2.w, fmaf(p0, x0.w, fmaf(p1, x1.w, fmaf(p2, x2.w, be)))))), 0.f);
    *(float4*)(ob + (size_t)o * TV + tq) = r;
  }
}

extern "C" void kernel_launch(void* const* d_in, const int* in_sizes, int n_in,
                              void* d_out, int out_size, void* d_ws, size_t ws_size,
                              hipStream_t stream)
{
  (void)in_sizes; (void)n_in; (void)out_size; (void)ws_size;
  const float* x     = (const float*)d_in[0];
  const float* w1    = (const float*)d_in[1];
  const float* b1    = (const float*)d_in[2];
  const float* w2    = (const float*)d_in[3];
  const float* b2    = (const float*)d_in[4];
  const float* cw    = (const float*)d_in[5];
  const float* cb    = (const float*)d_in[6];
  const float* cg_   = (const float*)d_in[7];
  const float* cbeta = (const float*)d_in[8];
  const float* PA    = (const float*)d_in[9];
  const float* alpha = (const float*)d_in[10];
  const float* c2w   = (const float*)d_in[11];
  const float* c2b   = (const float*)d_in[12];
  const float* bng   = (const float*)d_in[13];
  const float* bnb   = (const float*)d_in[14];
  const float* pw    = (const float*)d_in[15];
  const float* pb    = (const float*)d_in[16];
  const float* pg    = (const float*)d_in[17];
  const float* pbeta = (const float*)d_in[18];
  float* out = (float*)d_out;

  char* ws = (char*)d_ws;
  double* spart  = (double*)(ws + 0);          // 512*5*8     = 20480
  float*  gpart  = (float*)(ws + 20480);       // 512*2688*4  = 5505024 -> 5525504
  float*  a3part = (float*)(ws + 5525504);     // 128*289*4   = 147968  -> 5673472
  double* gramF  = (double*)(ws + 5673472);    // 2652*8      = 21216   -> 5694688

  hipLaunchKernelGGL(k1, dim3(512), dim3(256), 0, stream,
                     x, w1, b1, w2, b2, cw, cb, spart, gpart);
  hipLaunchKernelGGL(k2, dim3(2, Nn), dim3(256), 0, stream,
                     x, spart, gpart, w1, b1, w2, b2, cw, cb, cg_, cbeta, a3part, gramF);
  hipLaunchKernelGGL(k3, dim3(512), dim3(256), 0, stream,
                     x, PA, alpha, a3part, gramF, c2w, c2b, bng, bnb,
                     pw, pb, pg, pbeta, out);
}